// Round 8
// baseline (133.563 us; speedup 1.0000x reference)
//
#include <hip/hip_runtime.h>

// Sizes fixed by the reference.
#define BB 4
#define SS 4096
#define DM 1024
#define HID 64
#define KTOP 204
static constexpr size_t PATTERN_N = (size_t)BB * SS * SS;  // 67108864

typedef float f4 __attribute__((ext_vector_type(4)));
typedef float f32x4 __attribute__((ext_vector_type(4)));
typedef _Float16 h8v __attribute__((ext_vector_type(8)));

// d_out scratch layout (float offsets), all < PATTERN_N, overwritten by K3:
//   [0,      16384) : scores [B*S] f32
//   [16384,  49152) : Wfrag_hi  65536 f16 (pre-swizzled MFMA B-fragments)
//   [49152,  81920) : Wfrag_lo  65536 f16
#define SCORES_OFF 0
#define WHF_OFF 16384
#define WLF_OFF 49152

// ---------------------------------------------------------------------------
// K0: W1 (f32 [1024][64]) -> fp16 hi/lo MFMA B-fragments, scaled by 1024.
// frag[(k0*4+nt)*64 + lane][j] holds W[k0*32 + 8*(lane>>4) + j][nt*16+(lane&15)]
// (verified R7: absmax=0).
// ---------------------------------------------------------------------------
__global__ __launch_bounds__(256) void k0_wconv(
    const float* __restrict__ W1, _Float16* __restrict__ whf,
    _Float16* __restrict__ wlf) {
  const int gid = blockIdx.x * 256 + threadIdx.x;  // 8192 total
  const int l = gid & 63;
  const int nt = (gid >> 6) & 3;
  const int k0 = gid >> 8;  // 0..31
  const int kb = k0 * 32 + (l >> 4) * 8;
  const int n = nt * 16 + (l & 15);
  h8v hi, lo;
#pragma unroll
  for (int j = 0; j < 8; ++j) {
    float w = W1[(size_t)(kb + j) * HID + n] * 1024.f;
    _Float16 h = (_Float16)w;
    hi[j] = h;
    lo[j] = (_Float16)((w - (float)h) * 4096.f);
  }
  reinterpret_cast<h8v*>(whf)[(k0 * 4 + nt) * 64 + l] = hi;
  reinterpret_cast<h8v*>(wlf)[(k0 * 4 + nt) * 64 + l] = lo;
}

// ---------------------------------------------------------------------------
// K1: scores = relu(emb @ W1 + b1) @ W2 + b2, fp16 hi/lo 3-MFMA fp32 emu
// (numerics identical to R7, absmax=0). NEW decomposition:
//   512 blocks x 4 waves = 2048 waves (2/SIMD, full GPU).
//   wave = (32 tokens, nt = wv): 2 M-tiles x 1 N-tile, K=1024 in 32 steps.
//   Ping-pong register sets via macros (no rotation copies); ALL prefetch
//   loads unconditional (last step clamped) -> no conditional defs/spills.
//   Per step: 4 A-loads (f4, line-coalesced), 2 B-loads (own nt slice only).
// ---------------------------------------------------------------------------
#define LOAD_SET(KK, A, BH, BL)                         \
  {                                                     \
    const int koff_ = (KK) * 32;                        \
    A##0 = *reinterpret_cast<const f4*>(ap0 + koff_);   \
    A##1 = *reinterpret_cast<const f4*>(ap0 + koff_ + 4); \
    A##2 = *reinterpret_cast<const f4*>(ap1 + koff_);   \
    A##3 = *reinterpret_cast<const f4*>(ap1 + koff_ + 4); \
    BH = bhp0[(size_t)(KK) * 256];                      \
    BL = blp0[(size_t)(KK) * 256];                      \
  }

#define CONV4(SRC, DSTH, DSTL, O)                       \
  {                                                     \
    _Float16 h_;                                        \
    float x_;                                           \
    x_ = SRC[0]; h_ = (_Float16)x_; DSTH[O + 0] = h_;   \
    DSTL[O + 0] = (_Float16)((x_ - (float)h_) * 4096.f); \
    x_ = SRC[1]; h_ = (_Float16)x_; DSTH[O + 1] = h_;   \
    DSTL[O + 1] = (_Float16)((x_ - (float)h_) * 4096.f); \
    x_ = SRC[2]; h_ = (_Float16)x_; DSTH[O + 2] = h_;   \
    DSTL[O + 2] = (_Float16)((x_ - (float)h_) * 4096.f); \
    x_ = SRC[3]; h_ = (_Float16)x_; DSTH[O + 3] = h_;   \
    DSTL[O + 3] = (_Float16)((x_ - (float)h_) * 4096.f); \
  }

#define COMPUTE(A, BH, BL)                                            \
  {                                                                   \
    h8v ah0_, al0_, ah1_, al1_;                                       \
    CONV4(A##0, ah0_, al0_, 0);                                       \
    CONV4(A##1, ah0_, al0_, 4);                                       \
    CONV4(A##2, ah1_, al1_, 0);                                       \
    CONV4(A##3, ah1_, al1_, 4);                                       \
    acc00 = __builtin_amdgcn_mfma_f32_16x16x32_f16(ah0_, BH, acc00, 0, 0, 0); \
    acc10 = __builtin_amdgcn_mfma_f32_16x16x32_f16(al0_, BH, acc10, 0, 0, 0); \
    acc10 = __builtin_amdgcn_mfma_f32_16x16x32_f16(ah0_, BL, acc10, 0, 0, 0); \
    acc01 = __builtin_amdgcn_mfma_f32_16x16x32_f16(ah1_, BH, acc01, 0, 0, 0); \
    acc11 = __builtin_amdgcn_mfma_f32_16x16x32_f16(al1_, BH, acc11, 0, 0, 0); \
    acc11 = __builtin_amdgcn_mfma_f32_16x16x32_f16(ah1_, BL, acc11, 0, 0, 0); \
  }

__global__ __launch_bounds__(256, 2) void k1_mfma(
    const float* __restrict__ emb, const _Float16* __restrict__ whf,
    const _Float16* __restrict__ wlf, const float* __restrict__ b1,
    const float* __restrict__ W2, const float* __restrict__ b2,
    float* __restrict__ scores) {
  __shared__ float lds3[4][32];
  const int tid = threadIdx.x;
  const int l = tid & 63;
  const int wv = tid >> 6;  // = nt (N-tile owned by this wave)
  const int tokg = blockIdx.x * 32;
  const int lrow = l & 15;
  const int lk8 = (l >> 4) * 8;

  const float* __restrict__ ap0 = emb + (size_t)(tokg + lrow) * DM + lk8;
  const float* __restrict__ ap1 = emb + (size_t)(tokg + 16 + lrow) * DM + lk8;
  const h8v* __restrict__ bhp0 =
      reinterpret_cast<const h8v*>(whf) + wv * 64 + l;
  const h8v* __restrict__ blp0 =
      reinterpret_cast<const h8v*>(wlf) + wv * 64 + l;

  f32x4 acc00 = {0.f, 0.f, 0.f, 0.f}, acc01 = {0.f, 0.f, 0.f, 0.f};
  f32x4 acc10 = {0.f, 0.f, 0.f, 0.f}, acc11 = {0.f, 0.f, 0.f, 0.f};

  f4 aA0, aA1, aA2, aA3, aB0, aB1, aB2, aB3;
  h8v bhA, blA, bhB, blB;

  LOAD_SET(0, aA, bhA, blA);
#pragma unroll 1
  for (int kk = 0; kk < 16; ++kk) {
    const int k0 = kk * 2;
    const int kn2 = (k0 + 2 < 32) ? k0 + 2 : 31;  // clamp: unconditional load
    LOAD_SET(k0 + 1, aB, bhB, blB);
    COMPUTE(aA, bhA, blA);
    LOAD_SET(kn2, aA, bhA, blA);
    COMPUTE(aB, bhB, blB);
  }

  // Epilogue: h = relu((acc0 + 2^-12 acc1)*2^-10 + b1); partial p = h@W2
  // over this wave's 16 hidden cols; shfl-reduce over lanes sharing l>>4;
  // cross-wave (nt) combine via LDS.
  const float b1v = b1[wv * 16 + lrow];
  const float w2v = W2[wv * 16 + lrow];
  f32x4 accA[2][1];  // silence none; direct use below
#pragma unroll
  for (int mt = 0; mt < 2; ++mt) {
#pragma unroll
    for (int i = 0; i < 4; ++i) {
      float a0 = (mt == 0) ? acc00[i] : acc01[i];
      float a1 = (mt == 0) ? acc10[i] : acc11[i];
      float hs = (a0 + 0x1p-12f * a1) * 0x1p-10f + b1v;
      hs = hs > 0.f ? hs : 0.f;
      float p = hs * w2v;
      p += __shfl_xor(p, 1, 64);
      p += __shfl_xor(p, 2, 64);
      p += __shfl_xor(p, 4, 64);
      p += __shfl_xor(p, 8, 64);
      if (lrow == 0) lds3[wv][mt * 16 + (l >> 4) * 4 + i] = p;
    }
  }
  __syncthreads();
  if (tid < 32) {
    scores[tokg + tid] = lds3[0][tid] + lds3[1][tid] + lds3[2][tid] +
                         lds3[3][tid] + b2[0];
  }
}

// ---------------------------------------------------------------------------
// K2: exact top-k by rank counting (jax.lax.top_k order: descending, ties ->
// lower index). 256 blocks x 256 threads; 4 waves split j-range.
// ---------------------------------------------------------------------------
__global__ __launch_bounds__(256) void k2_topk(
    const float* __restrict__ scores, float* __restrict__ out_idx) {
  __shared__ __align__(16) float sc[SS];
  __shared__ int red[256];
  const int tid = threadIdx.x;
  const int b = blockIdx.x >> 6;
  const int ic = blockIdx.x & 63;
  const float* row = scores + (size_t)b * SS;
#pragma unroll
  for (int q = 0; q < 4; ++q) {
    int f = tid + q * 256;  // float4 index
    *reinterpret_cast<f4*>(&sc[f * 4]) =
        *reinterpret_cast<const f4*>(&row[f * 4]);
  }
  __syncthreads();
  const int il = tid & 63;
  const int part = tid >> 6;  // j quarter (wave-uniform)
  const int i = ic * 64 + il;
  const float si = sc[i];
  const f4* s4 = reinterpret_cast<const f4*>(sc);
  int cnt = 0;
  for (int j4 = part * 256; j4 < part * 256 + 256; ++j4) {
    f4 v = s4[j4];  // broadcast LDS read
    int j = j4 * 4;
    cnt += (int)(v.x > si) + (int)((v.x == si) & (j + 0 < i));
    cnt += (int)(v.y > si) + (int)((v.y == si) & (j + 1 < i));
    cnt += (int)(v.z > si) + (int)((v.z == si) & (j + 2 < i));
    cnt += (int)(v.w > si) + (int)((v.w == si) & (j + 3 < i));
  }
  red[tid] = cnt;
  __syncthreads();
  if (tid < 64) {
    int tot = red[tid] + red[tid + 64] + red[tid + 128] + red[tid + 192];
    if (tot < KTOP) out_idx[b * KTOP + tot] = (float)(ic * 64 + tid);
  }
}

// ---------------------------------------------------------------------------
// K3: attention_pattern[b,i,:] = col_mask[b,:] for all i.
// 1024 blocks x 256 threads; 16 rows/block; NT stores (R2/R3 A/B:
// NT ~16us — L3 absorbs same-footprint rewrites; plain ~69us).
// ---------------------------------------------------------------------------
__global__ __launch_bounds__(256) void k3_pattern(
    const float* __restrict__ out_idx, float* __restrict__ pat) {
  __shared__ __align__(16) float mask[SS];
  const int tid = threadIdx.x;
  const int b  = blockIdx.x >> 8;            // 256 blocks per batch
  const int r0 = (blockIdx.x & 255) * 16;
  const f4 zero = (f4){0.f, 0.f, 0.f, 0.f};
#pragma unroll
  for (int q = 0; q < 4; ++q) {
    int f = tid + q * 256;
    *reinterpret_cast<f4*>(&mask[f * 4]) = zero;
  }
  __syncthreads();
  if (tid < KTOP) {
    int c = (int)out_idx[b * KTOP + tid];
    mask[c] = 1.0f / (float)KTOP;
  }
  __syncthreads();
  const f4 m0 = *reinterpret_cast<const f4*>(&mask[(tid)*4]);
  const f4 m1 = *reinterpret_cast<const f4*>(&mask[(tid + 256) * 4]);
  const f4 m2 = *reinterpret_cast<const f4*>(&mask[(tid + 512) * 4]);
  const f4 m3 = *reinterpret_cast<const f4*>(&mask[(tid + 768) * 4]);
  for (int r = 0; r < 16; ++r) {
    f4* p4 = reinterpret_cast<f4*>(pat + ((size_t)b * SS + r0 + r) * SS);
    __builtin_nontemporal_store(m0, &p4[tid]);
    __builtin_nontemporal_store(m1, &p4[tid + 256]);
    __builtin_nontemporal_store(m2, &p4[tid + 512]);
    __builtin_nontemporal_store(m3, &p4[tid + 768]);
  }
}

extern "C" void kernel_launch(void* const* d_in, const int* in_sizes, int n_in,
                              void* d_out, int out_size, void* d_ws,
                              size_t ws_size, hipStream_t stream) {
  const float* emb = (const float*)d_in[0];
  const float* W1  = (const float*)d_in[1];
  const float* b1  = (const float*)d_in[2];
  const float* W2  = (const float*)d_in[3];
  const float* b2  = (const float*)d_in[4];
  float* out = (float*)d_out;
  float* pat     = out;              // [B,S,S] pattern
  float* out_idx = out + PATTERN_N;  // [B,KTOP] indices as float
  float* scores = out + SCORES_OFF;
  _Float16* whf = (_Float16*)(out + WHF_OFF);
  _Float16* wlf = (_Float16*)(out + WLF_OFF);

  k0_wconv<<<dim3(32), dim3(256), 0, stream>>>(W1, whf, wlf);
  k1_mfma<<<dim3((BB * SS) / 32), dim3(256), 0, stream>>>(emb, whf, wlf, b1,
                                                          W2, b2, scores);
  k2_topk<<<dim3(BB * (SS / 64)), dim3(256), 0, stream>>>(scores, out_idx);
  k3_pattern<<<dim3((BB * SS) / 16), dim3(256), 0, stream>>>(out_idx, pat);
}